// Round 16
// baseline (170.292 us; speedup 1.0000x reference)
//
#include <hip/hip_runtime.h>

// Problem constants (fixed by reference)
constexpr int N_  = 10000;   // nodes (< 65536 -> u16 src)
constexpr int E_  = 320000;  // edges
constexpr int F1  = 33;      // input features
constexpr int H   = 32;      // hidden
constexpr int G   = 64;      // graphs
constexpr int CAP = 96;      // padded CSR slots/node (deg~Poisson(32), P(overflow)~1e-18/node)
constexpr int NB_ = 1280;    // node-blocks of 8 (covers 10240 >= N_)
constexpr int ROW = CAP * 8; // 768 dwords per node-block row in transposed meta

constexpr int EBLK = E_ / 256;   // 1250 edge blocks
constexpr int PBLK = N_ / 8;     // 1250 node-group tasks (8 nodes x 32 lanes)
constexpr int SLICES = 32;
constexpr int PAIRS  = 16;       // feature pairs per agg block (2 x 40KB LDS tables)
constexpr int CHUNKS = 32;       // 512 agg blocks of 1024 thr; 80KB LDS -> 2 blocks/CU
constexpr int TILE   = 320;
constexpr int AT     = 1024;     // 16 waves x 8 nodes = 128 nodes/iter
constexpr int ITERS  = 3;        // covers 384 >= 320 (64-node overlap: benign dup writes)

// round-to-nearest-even f32 -> bf16 (low 16 bits)
__device__ __forceinline__ unsigned bf16r(float x) {
    unsigned u = __float_as_uint(x);
    return (u + 0x7FFFu + ((u >> 16) & 1u)) >> 16;
}

// transposed meta slot address: node n, slot pos
__device__ __forceinline__ size_t mslot(int n, int pos) {
    return (size_t)(n >> 3) * ROW + (size_t)(pos >> 3) * 64 + (n & 7) * 8 + (pos & 7);
}

// ---------------- build: padded CSR (transposed) + layer-1 precompute ----------------

__global__ __launch_bounds__(256) void k_build_pre1(
        const int* __restrict__ ei, const float* __restrict__ ea,
        const float* __restrict__ x, const int* __restrict__ batch,
        const float* __restrict__ A, const float* __restrict__ Bm,
        const float* __restrict__ Rw, const float* __restrict__ bias,
        int* __restrict__ counts, unsigned* __restrict__ meta2,
        unsigned* __restrict__ UVs, float* __restrict__ Rs,
        int* __restrict__ startsP) {
    __shared__ unsigned s_uv[32][9];
    __shared__ float    s_r[32][9];
    if (blockIdx.x < EBLK) {
        int e = blockIdx.x * 256 + threadIdx.x;
        int s = ei[e];
        int d = ei[E_ + e];
        int pos = atomicAdd(&counts[d], 1);
        meta2[mslot(d, pos)] = (unsigned)s | (bf16r(ea[e]) << 16);
    } else {
        int base8 = (blockIdx.x - EBLK) * 8;
        int grp = threadIdx.x >> 5;
        int f = threadIdx.x & 31;
        int node = base8 + grp;
        if (f == 0) {   // graph-boundary detection (batch sorted)
            int b = batch[node];
            int bp = (node == 0) ? -1 : batch[node - 1];
            if (b != bp) startsP[b] = node + 1;
        }
        float u = 0.f, v = 0.f, r = bias[f];
        const float* xr = x + (size_t)node * F1;
        #pragma unroll
        for (int k = 0; k < F1; ++k) {
            float xv = xr[k];
            u = fmaf(xv, A[k * H + f], u);
            v = fmaf(xv, Bm[k * H + f], v);
            r = fmaf(xv, Rw[k * H + f], r);
        }
        s_uv[f][grp] = bf16r(u) | (bf16r(v) << 16);
        s_r[f][grp]  = r;
        __syncthreads();
        int fo = threadIdx.x >> 3;
        int nl = threadIdx.x & 7;
        UVs[(size_t)fo * N_ + base8 + nl] = s_uv[fo][nl];
        Rs [(size_t)fo * N_ + base8 + nl] = s_r [fo][nl];
    }
}

// ---------------- per-layer precompute from slice-major h ----------------

__global__ __launch_bounds__(256) void k_pre(
        const float* __restrict__ Hs,
        const float* __restrict__ A, const float* __restrict__ Bm,
        const float* __restrict__ Rw, const float* __restrict__ bias,
        unsigned* __restrict__ UVs, float* __restrict__ Rs) {
    __shared__ unsigned s_uv[32][9];
    __shared__ float    s_r[32][9];
    int base8 = blockIdx.x * 8;
    int grp = threadIdx.x >> 5;
    int f = threadIdx.x & 31;
    int node = base8 + grp;
    float hv = Hs[(size_t)f * N_ + node];
    float u = 0.f, v = 0.f, r = bias[f];
    #pragma unroll
    for (int k = 0; k < H; ++k) {
        float hk = __shfl(hv, k, 32);
        u = fmaf(hk, A[k * H + f], u);
        v = fmaf(hk, Bm[k * H + f], v);
        r = fmaf(hk, Rw[k * H + f], r);
    }
    s_uv[f][grp] = bf16r(u) | (bf16r(v) << 16);
    s_r[f][grp]  = r;
    __syncthreads();
    int fo = threadIdx.x >> 3;
    int nl = threadIdx.x & 7;
    UVs[(size_t)fo * N_ + base8 + nl] = s_uv[fo][nl];
    Rs [(size_t)fo * N_ + base8 + nl] = s_r [fo][nl];
}

// ---------------- LDS-sliced conv aggregation: 2 features per block ----------------
// block = (feature pair, 320-node chunk). LDS = interleaved pair table {w_f0,w_f1}[N]
// (80 KB -> 2 blocks/CU, 32 waves/CU). One meta load feeds both features; each gather
// is one 8B LDS read. 16 waves x (8 nodes x 8 slots), 3 iters (64-node benign overlap).

__global__ __launch_bounds__(1024, 8) void k_agg_lds(
        const int* __restrict__ counts, const unsigned* __restrict__ meta2,
        const unsigned* __restrict__ UVs, const float* __restrict__ Rs,
        float* __restrict__ Hs) {
    __shared__ __align__(16) unsigned uvl[2 * N_];   // 80 KB
    int s0    = (blockIdx.x & (PAIRS - 1)) * 2;
    int s1    = s0 + 1;
    int chunk = blockIdx.x >> 4;

    int l   = threadIdx.x & 63;
    int wav = threadIdx.x >> 6;      // 0..15
    int j0  = l & 7;                 // slot within group
    int nl  = l >> 3;                // node within wave (0..7)

    // ---- initial prefetch (overlaps LDS fill) ----
    int cbase = chunk * TILE + wav * 8;
    int node = cbase + nl;
    int nc = min(node, N_ - 1);
    int dg = (node < N_) ? counts[nc] : 0;
    float rv0 = Rs[(size_t)s0 * N_ + nc];
    float rv1 = Rs[(size_t)s1 * N_ + nc];
    const unsigned* mrow = meta2 + (size_t)min(cbase >> 3, NB_ - 1) * ROW + l;
    unsigned m0 = mrow[0], m1 = mrow[64], m2 = mrow[128],
             m3 = mrow[192], m4 = mrow[256], m5 = mrow[320];

    // ---- fill LDS: interleave the two per-feature UV tables ----
    const unsigned* p0 = UVs + (size_t)s0 * N_;
    const unsigned* p1 = UVs + (size_t)s1 * N_;
    #pragma unroll
    for (int i = 0; i < 3; ++i) {
        int q = i * AT + (int)threadIdx.x;        // group of 4 nodes
        if (q * 4 + 4 <= N_) {
            uint4 a = *reinterpret_cast<const uint4*>(p0 + q * 4);
            uint4 b = *reinterpret_cast<const uint4*>(p1 + q * 4);
            *reinterpret_cast<uint4*>(&uvl[q * 8])     = make_uint4(a.x, b.x, a.y, b.y);
            *reinterpret_cast<uint4*>(&uvl[q * 8 + 4]) = make_uint4(a.z, b.z, a.w, b.w);
        }
    }
    __syncthreads();

    for (int it = 0; it < ITERS; ++it) {
        // ---- prefetch next group (128 nodes ahead) ----
        int nbase = cbase + 128;
        int nnode = nbase + nl;
        int nnc = min(nnode, N_ - 1);
        int ndg = 0; float nrv0 = 0.f, nrv1 = 0.f;
        unsigned n0 = 0, n1 = 0, n2 = 0, n3 = 0, n4 = 0, n5 = 0;
        if (it < ITERS - 1) {
            ndg = (nnode < N_) ? counts[nnc] : 0;
            nrv0 = Rs[(size_t)s0 * N_ + nnc];
            nrv1 = Rs[(size_t)s1 * N_ + nnc];
            const unsigned* nmr = meta2 + (size_t)min(nbase >> 3, NB_ - 1) * ROW + l;
            n0 = nmr[0]; n1 = nmr[64]; n2 = nmr[128];
            n3 = nmr[192]; n4 = nmr[256]; n5 = nmr[320];
        }

        // ---- compute current group: always 6 slot groups, both features ----
        float acc0 = 0.f, acc1 = 0.f;
        auto slot = [&](int p, unsigned mv) {
            unsigned idx = min(mv & 0xFFFFu, (unsigned)(N_ - 1));
            uint2 w = *reinterpret_cast<const uint2*>(uvl + 2 * idx);
            float a = __uint_as_float(mv & 0xFFFF0000u);        // a (bf16 hi)
            float t0 = fmaf(a, __uint_as_float(w.x << 16),
                            __uint_as_float(w.x & 0xFFFF0000u));
            float t1 = fmaf(a, __uint_as_float(w.y << 16),
                            __uint_as_float(w.y & 0xFFFF0000u));
            if (j0 + 8 * p < dg) { acc0 += t0; acc1 += t1; }
        };
        slot(0, m0); slot(1, m1); slot(2, m2);
        slot(3, m3); slot(4, m4); slot(5, m5);
        if (__any(dg > 48)) {                  // rare deep-node tail (~2% of waves)
            const unsigned* trow = meta2 + (size_t)min(cbase >> 3, NB_ - 1) * ROW + l;
            for (int p = 6; __any(j0 + 8 * p < dg); ++p)
                slot(p, trow[p * 64]);
        }
        acc0 += __shfl_xor(acc0, 1); acc1 += __shfl_xor(acc1, 1);
        acc0 += __shfl_xor(acc0, 2); acc1 += __shfl_xor(acc1, 2);
        acc0 += __shfl_xor(acc0, 4); acc1 += __shfl_xor(acc1, 4);
        if (j0 == 0 && node < N_) {
            Hs[(size_t)s0 * N_ + node] = fmaxf(rv0 + acc0, 0.f);
            Hs[(size_t)s1 * N_ + node] = fmaxf(rv1 + acc1, 0.f);
        }

        cbase = nbase; node = nnode; nc = nnc; dg = ndg; rv0 = nrv0; rv1 = nrv1;
        m0 = n0; m1 = n1; m2 = n2; m3 = n3; m4 = n4; m5 = n5;
    }
}

// ---------------- per-graph pooling + readout: 64 independent blocks, NO atomics ----------

__global__ __launch_bounds__(256) void k_pool(
        const float* __restrict__ Hs, const int* __restrict__ startsP,
        const float* __restrict__ w1, const float* __restrict__ b1,
        const float* __restrict__ w2, const float* __restrict__ b2,
        float* __restrict__ out) {
    __shared__ int sst[G];
    __shared__ float ga[32], gm[32], gx[32];
    int tid = threadIdx.x;
    if (tid < G) sst[tid] = startsP[tid];
    __syncthreads();
    int g = blockIdx.x;
    int sp = sst[g];
    int s = 0, e = 0;
    if (sp != 0) {
        s = sp - 1;
        e = N_;
        for (int j = g + 1; j < G; ++j)
            if (sst[j]) { e = sst[j] - 1; break; }
    }
    int f = tid >> 3, oct = tid & 7;
    float sum = 0.f, mx = 0.f;
    for (int n = s + oct; n < e; n += 8) {
        float w = Hs[(size_t)f * N_ + n];
        sum += w;
        mx = fmaxf(mx, w);
    }
    sum += __shfl_xor(sum, 1); mx = fmaxf(mx, __shfl_xor(mx, 1));
    sum += __shfl_xor(sum, 2); mx = fmaxf(mx, __shfl_xor(mx, 2));
    sum += __shfl_xor(sum, 4); mx = fmaxf(mx, __shfl_xor(mx, 4));
    if (oct == 0) {
        float c = fmaxf((float)(e - s), 1.0f);
        ga[f] = sum;
        gm[f] = sum / c;
        gx[f] = mx;
    }
    __syncthreads();
    if (tid < 32) {
        float hacc = b1[tid];
        #pragma unroll
        for (int k = 0; k < H; ++k) {
            hacc = fmaf(ga[k], w1[k * H + tid], hacc);
            hacc = fmaf(gm[k], w1[(H + k) * H + tid], hacc);
            hacc = fmaf(gx[k], w1[(2 * H + k) * H + tid], hacc);
        }
        float hid = fmaxf(hacc, 0.f);
        float p0 = hid * w2[tid * 2 + 0];
        float p1 = hid * w2[tid * 2 + 1];
        #pragma unroll
        for (int offq = 16; offq; offq >>= 1) {
            p0 += __shfl_xor(p0, offq, 32);
            p1 += __shfl_xor(p1, offq, 32);
        }
        if (tid == 0) {
            float l0 = p0 + b2[0], l1 = p1 + b2[1];
            float m = fmaxf(l0, l1);
            float lse = m + logf(expf(l0 - m) + expf(l1 - m));
            out[g * 2 + 0] = l0 - lse;
            out[g * 2 + 1] = l1 - lse;
        }
    }
}

// ---------------- launch ----------------

extern "C" void kernel_launch(void* const* d_in, const int* in_sizes, int n_in,
                              void* d_out, int out_size, void* d_ws, size_t ws_size,
                              hipStream_t stream) {
    const float* x      = (const float*)d_in[0];
    const int*   ei     = (const int*)  d_in[1];
    const float* ea     = (const float*)d_in[2];
    const int*   batch  = (const int*)  d_in[3];
    const float* nn_w1  = (const float*)d_in[4];
    const float* nn_b1  = (const float*)d_in[5];
    const float* root1  = (const float*)d_in[6];
    const float* bias1  = (const float*)d_in[7];
    const float* nn_w2  = (const float*)d_in[8];
    const float* nn_b2  = (const float*)d_in[9];
    const float* root2  = (const float*)d_in[10];
    const float* bias2  = (const float*)d_in[11];
    const float* nn_w3  = (const float*)d_in[12];
    const float* nn_b3  = (const float*)d_in[13];
    const float* root3  = (const float*)d_in[14];
    const float* bias3  = (const float*)d_in[15];
    const float* lin1_w = (const float*)d_in[16];
    const float* lin1_b = (const float*)d_in[17];
    const float* lin2_w = (const float*)d_in[18];
    const float* lin2_b = (const float*)d_in[19];
    float* out = (float*)d_out;

    char* ws = (char*)d_ws;
    size_t off = 0;
    auto alloc = [&](size_t bytes) -> void* {
        void* p = ws + off;
        off += (bytes + 255) & ~(size_t)255;
        return p;
    };
    // zero-init chunk: counts | startsP
    const size_t zbytes = N_ * sizeof(int) + G * sizeof(int);
    char* zchunk = (char*)alloc(zbytes);
    int*  counts  = (int*)zchunk;
    int*  startsP = (int*)(zchunk + N_ * sizeof(int));
    unsigned* meta2 = (unsigned*)alloc((size_t)NB_ * ROW * sizeof(unsigned)); // 3.93 MB
    unsigned* UVs1 = (unsigned*)alloc((size_t)H * N_ * sizeof(unsigned));
    unsigned* UVs2 = (unsigned*)alloc((size_t)H * N_ * sizeof(unsigned));
    unsigned* UVs3 = (unsigned*)alloc((size_t)H * N_ * sizeof(unsigned));
    float* Rs1 = (float*)alloc((size_t)H * N_ * sizeof(float));
    float* Rs2 = (float*)alloc((size_t)H * N_ * sizeof(float));
    float* Rs3 = (float*)alloc((size_t)H * N_ * sizeof(float));
    float* h1  = (float*)alloc((size_t)H * N_ * sizeof(float));   // slice-major
    float* h2  = (float*)alloc((size_t)H * N_ * sizeof(float));
    float* h3  = (float*)alloc((size_t)H * N_ * sizeof(float));

    hipMemsetAsync(zchunk, 0, zbytes, stream);

    k_build_pre1<<<EBLK + PBLK, 256, 0, stream>>>(ei, ea, x, batch,
                                                  nn_w1, nn_b1, root1, bias1,
                                                  counts, meta2, UVs1, Rs1, startsP);

    k_agg_lds<<<PAIRS * CHUNKS, AT, 0, stream>>>(counts, meta2, UVs1, Rs1, h1);
    k_pre    <<<PBLK, 256, 0, stream>>>(h1, nn_w2, nn_b2, root2, bias2, UVs2, Rs2);
    k_agg_lds<<<PAIRS * CHUNKS, AT, 0, stream>>>(counts, meta2, UVs2, Rs2, h2);
    k_pre    <<<PBLK, 256, 0, stream>>>(h2, nn_w3, nn_b3, root3, bias3, UVs3, Rs3);
    k_agg_lds<<<PAIRS * CHUNKS, AT, 0, stream>>>(counts, meta2, UVs3, Rs3, h3);

    k_pool<<<G, 256, 0, stream>>>(h3, startsP, lin1_w, lin1_b, lin2_w, lin2_b, out);
}

// Round 17
// 168.848 us; speedup vs baseline: 1.0085x; 1.0085x over previous
//
#include <hip/hip_runtime.h>

// Problem constants (fixed by reference)
constexpr int N_  = 10000;   // nodes (< 65536 -> u16 src)
constexpr int E_  = 320000;  // edges
constexpr int F1  = 33;      // input features
constexpr int H   = 32;      // hidden
constexpr int G   = 64;      // graphs
constexpr int CAP = 96;      // padded CSR slots/node (deg~Poisson(32), P(overflow)~1e-18/node)
constexpr int NB_ = 1280;    // node-blocks of 8 (covers 10240 >= N_)
constexpr int ROW = CAP * 8; // 768 dwords per node-block row in transposed meta

constexpr int EBLK = E_ / 256;   // 1250 edge blocks
constexpr int PBLK = N_ / 8;     // 1250 node-group tasks (8 nodes x 32 lanes)
constexpr int SLICES = 32;
constexpr int CHUNKS = 16;       // 512 agg blocks
constexpr int TILE   = 640;      // 16*640 = 10240 >= N_
// agg blocks: 1024 threads = 16 waves x 8 nodes -> 128 nodes/iter, 5 iters.
// 2 blocks/CU (thread-capped) x 16 waves = 32 waves/CU (100% wave occupancy).
constexpr int AT    = 1024;
constexpr int ITERS = TILE / 128;

// round-to-nearest-even f32 -> bf16 (low 16 bits)
__device__ __forceinline__ unsigned bf16r(float x) {
    unsigned u = __float_as_uint(x);
    return (u + 0x7FFFu + ((u >> 16) & 1u)) >> 16;
}

// transposed meta slot address: node n, slot pos
__device__ __forceinline__ size_t mslot(int n, int pos) {
    return (size_t)(n >> 3) * ROW + (size_t)(pos >> 3) * 64 + (n & 7) * 8 + (pos & 7);
}

// ---------------- build: padded CSR (transposed) + layer-1 precompute ----------------

__global__ __launch_bounds__(256) void k_build_pre1(
        const int* __restrict__ ei, const float* __restrict__ ea,
        const float* __restrict__ x, const int* __restrict__ batch,
        const float* __restrict__ A, const float* __restrict__ Bm,
        const float* __restrict__ Rw, const float* __restrict__ bias,
        int* __restrict__ counts, unsigned* __restrict__ meta2,
        unsigned* __restrict__ UVs, float* __restrict__ Rs,
        int* __restrict__ startsP) {
    __shared__ unsigned s_uv[32][9];
    __shared__ float    s_r[32][9];
    if (blockIdx.x < EBLK) {
        int e = blockIdx.x * 256 + threadIdx.x;
        int s = ei[e];
        int d = ei[E_ + e];
        int pos = atomicAdd(&counts[d], 1);
        meta2[mslot(d, pos)] = (unsigned)s | (bf16r(ea[e]) << 16);
    } else {
        int base8 = (blockIdx.x - EBLK) * 8;
        int grp = threadIdx.x >> 5;
        int f = threadIdx.x & 31;
        int node = base8 + grp;
        if (f == 0) {   // graph-boundary detection (batch sorted)
            int b = batch[node];
            int bp = (node == 0) ? -1 : batch[node - 1];
            if (b != bp) startsP[b] = node + 1;
        }
        float u = 0.f, v = 0.f, r = bias[f];
        const float* xr = x + (size_t)node * F1;
        #pragma unroll
        for (int k = 0; k < F1; ++k) {
            float xv = xr[k];
            u = fmaf(xv, A[k * H + f], u);
            v = fmaf(xv, Bm[k * H + f], v);
            r = fmaf(xv, Rw[k * H + f], r);
        }
        s_uv[f][grp] = bf16r(u) | (bf16r(v) << 16);
        s_r[f][grp]  = r;
        __syncthreads();
        int fo = threadIdx.x >> 3;
        int nl = threadIdx.x & 7;
        UVs[(size_t)fo * N_ + base8 + nl] = s_uv[fo][nl];
        Rs [(size_t)fo * N_ + base8 + nl] = s_r [fo][nl];
    }
}

// ---------------- per-layer precompute from slice-major h ----------------

__global__ __launch_bounds__(256) void k_pre(
        const float* __restrict__ Hs,
        const float* __restrict__ A, const float* __restrict__ Bm,
        const float* __restrict__ Rw, const float* __restrict__ bias,
        unsigned* __restrict__ UVs, float* __restrict__ Rs) {
    __shared__ unsigned s_uv[32][9];
    __shared__ float    s_r[32][9];
    int base8 = blockIdx.x * 8;
    int grp = threadIdx.x >> 5;
    int f = threadIdx.x & 31;
    int node = base8 + grp;
    float hv = Hs[(size_t)f * N_ + node];
    float u = 0.f, v = 0.f, r = bias[f];
    #pragma unroll
    for (int k = 0; k < H; ++k) {
        float hk = __shfl(hv, k, 32);
        u = fmaf(hk, A[k * H + f], u);
        v = fmaf(hk, Bm[k * H + f], v);
        r = fmaf(hk, Rw[k * H + f], r);
    }
    s_uv[f][grp] = bf16r(u) | (bf16r(v) << 16);
    s_r[f][grp]  = r;
    __syncthreads();
    int fo = threadIdx.x >> 3;
    int nl = threadIdx.x & 7;
    UVs[(size_t)fo * N_ + base8 + nl] = s_uv[fo][nl];
    Rs [(size_t)fo * N_ + base8 + nl] = s_r [fo][nl];
}

// ---------------- LDS-sliced conv aggregation, 1024-thread blocks ----------------
// block = (slice s, 640-node chunk). LDS = full per-feature UV table (40 KB).
// 16 waves x (8 nodes x 8 slots); always-6 slot groups; rare deep-node tail via __any.

__global__ __launch_bounds__(1024, 8) void k_agg_lds(
        const int* __restrict__ counts, const unsigned* __restrict__ meta2,
        const unsigned* __restrict__ UVs, const float* __restrict__ Rs,
        float* __restrict__ Hs) {
    __shared__ __align__(16) unsigned uvl[N_];
    int s     = blockIdx.x & 31;
    int chunk = blockIdx.x >> 5;

    int l   = threadIdx.x & 63;
    int wav = threadIdx.x >> 6;      // 0..15
    int j0  = l & 7;                 // slot within group
    int nl  = l >> 3;                // node within wave (0..7)

    // ---- initial prefetch (overlaps LDS fill) ----
    int cbase = chunk * TILE + wav * 8;
    int node = cbase + nl;
    int nc = min(node, N_ - 1);
    int dg = (node < N_) ? counts[nc] : 0;
    float rv = Rs[(size_t)s * N_ + nc];
    const unsigned* mrow = meta2 + (size_t)(cbase >> 3) * ROW + l;
    unsigned m0 = mrow[0], m1 = mrow[64], m2 = mrow[128],
             m3 = mrow[192], m4 = mrow[256], m5 = mrow[320];

    // ---- fill LDS with this slice's UV table (coalesced 40 KB, 3 sweeps) ----
    const unsigned* srcp = UVs + (size_t)s * N_;
    #pragma unroll
    for (int i = 0; i < 3; ++i) {
        int d4 = (i * AT + (int)threadIdx.x) * 4;
        if (d4 + 4 <= N_) {
            uint4 t = *reinterpret_cast<const uint4*>(srcp + d4);
            *reinterpret_cast<uint4*>(&uvl[d4]) = t;
        }
    }
    __syncthreads();

    for (int it = 0; it < ITERS; ++it) {
        // ---- prefetch next group (128 nodes ahead) ----
        int nbase = cbase + 128;
        int nnode = nbase + nl;
        int nnc = min(nnode, N_ - 1);
        int ndg = 0; float nrv = 0.f;
        unsigned n0 = 0, n1 = 0, n2 = 0, n3 = 0, n4 = 0, n5 = 0;
        if (it < ITERS - 1) {
            ndg = (nnode < N_) ? counts[nnc] : 0;
            nrv = Rs[(size_t)s * N_ + nnc];
            const unsigned* nmr = meta2 + (size_t)(nbase >> 3) * ROW + l;
            n0 = nmr[0]; n1 = nmr[64]; n2 = nmr[128];
            n3 = nmr[192]; n4 = nmr[256]; n5 = nmr[320];
        }

        // ---- compute current group: always 6 slot groups (48 slots) ----
        float acc = 0.f;
        auto slot = [&](int p, unsigned mv) {
            unsigned idx = min(mv & 0xFFFFu, (unsigned)(N_ - 1));
            unsigned w = uvl[idx];
            float t = fmaf(__uint_as_float(mv & 0xFFFF0000u),   // a (bf16 hi)
                           __uint_as_float(w << 16),            // u
                           __uint_as_float(w & 0xFFFF0000u));   // v
            if (j0 + 8 * p < dg) acc += t;
        };
        slot(0, m0); slot(1, m1); slot(2, m2);
        slot(3, m3); slot(4, m4); slot(5, m5);
        if (__any(dg > 48)) {                  // rare deep-node tail (~2% of waves)
            const unsigned* trow = meta2 + (size_t)(cbase >> 3) * ROW + l;
            for (int p = 6; __any(j0 + 8 * p < dg); ++p)
                slot(p, trow[p * 64]);
        }
        acc += __shfl_xor(acc, 1);
        acc += __shfl_xor(acc, 2);
        acc += __shfl_xor(acc, 4);
        float h = fmaxf(rv + acc, 0.f);
        if (j0 == 0 && node < N_) Hs[(size_t)s * N_ + node] = h;

        cbase = nbase; node = nnode; nc = nnc; dg = ndg; rv = nrv;
        m0 = n0; m1 = n1; m2 = n2; m3 = n3; m4 = n4; m5 = n5;
    }
}

// ---------------- per-graph pooling + readout: 64 independent blocks, NO atomics ----------

__global__ __launch_bounds__(256) void k_pool(
        const float* __restrict__ Hs, const int* __restrict__ startsP,
        const float* __restrict__ w1, const float* __restrict__ b1,
        const float* __restrict__ w2, const float* __restrict__ b2,
        float* __restrict__ out) {
    __shared__ int sst[G];
    __shared__ float ga[32], gm[32], gx[32];
    int tid = threadIdx.x;
    if (tid < G) sst[tid] = startsP[tid];
    __syncthreads();
    int g = blockIdx.x;
    int sp = sst[g];
    int s = 0, e = 0;
    if (sp != 0) {
        s = sp - 1;
        e = N_;
        for (int j = g + 1; j < G; ++j)
            if (sst[j]) { e = sst[j] - 1; break; }
    }
    int f = tid >> 3, oct = tid & 7;
    float sum = 0.f, mx = 0.f;
    for (int n = s + oct; n < e; n += 8) {
        float w = Hs[(size_t)f * N_ + n];
        sum += w;
        mx = fmaxf(mx, w);
    }
    sum += __shfl_xor(sum, 1); mx = fmaxf(mx, __shfl_xor(mx, 1));
    sum += __shfl_xor(sum, 2); mx = fmaxf(mx, __shfl_xor(mx, 2));
    sum += __shfl_xor(sum, 4); mx = fmaxf(mx, __shfl_xor(mx, 4));
    if (oct == 0) {
        float c = fmaxf((float)(e - s), 1.0f);
        ga[f] = sum;
        gm[f] = sum / c;
        gx[f] = mx;
    }
    __syncthreads();
    if (tid < 32) {
        float hacc = b1[tid];
        #pragma unroll
        for (int k = 0; k < H; ++k) {
            hacc = fmaf(ga[k], w1[k * H + tid], hacc);
            hacc = fmaf(gm[k], w1[(H + k) * H + tid], hacc);
            hacc = fmaf(gx[k], w1[(2 * H + k) * H + tid], hacc);
        }
        float hid = fmaxf(hacc, 0.f);
        float p0 = hid * w2[tid * 2 + 0];
        float p1 = hid * w2[tid * 2 + 1];
        #pragma unroll
        for (int offq = 16; offq; offq >>= 1) {
            p0 += __shfl_xor(p0, offq, 32);
            p1 += __shfl_xor(p1, offq, 32);
        }
        if (tid == 0) {
            float l0 = p0 + b2[0], l1 = p1 + b2[1];
            float m = fmaxf(l0, l1);
            float lse = m + logf(expf(l0 - m) + expf(l1 - m));
            out[g * 2 + 0] = l0 - lse;
            out[g * 2 + 1] = l1 - lse;
        }
    }
}

// ---------------- launch ----------------

extern "C" void kernel_launch(void* const* d_in, const int* in_sizes, int n_in,
                              void* d_out, int out_size, void* d_ws, size_t ws_size,
                              hipStream_t stream) {
    const float* x      = (const float*)d_in[0];
    const int*   ei     = (const int*)  d_in[1];
    const float* ea     = (const float*)d_in[2];
    const int*   batch  = (const int*)  d_in[3];
    const float* nn_w1  = (const float*)d_in[4];
    const float* nn_b1  = (const float*)d_in[5];
    const float* root1  = (const float*)d_in[6];
    const float* bias1  = (const float*)d_in[7];
    const float* nn_w2  = (const float*)d_in[8];
    const float* nn_b2  = (const float*)d_in[9];
    const float* root2  = (const float*)d_in[10];
    const float* bias2  = (const float*)d_in[11];
    const float* nn_w3  = (const float*)d_in[12];
    const float* nn_b3  = (const float*)d_in[13];
    const float* root3  = (const float*)d_in[14];
    const float* bias3  = (const float*)d_in[15];
    const float* lin1_w = (const float*)d_in[16];
    const float* lin1_b = (const float*)d_in[17];
    const float* lin2_w = (const float*)d_in[18];
    const float* lin2_b = (const float*)d_in[19];
    float* out = (float*)d_out;

    char* ws = (char*)d_ws;
    size_t off = 0;
    auto alloc = [&](size_t bytes) -> void* {
        void* p = ws + off;
        off += (bytes + 255) & ~(size_t)255;
        return p;
    };
    // zero-init chunk: counts | startsP
    const size_t zbytes = N_ * sizeof(int) + G * sizeof(int);
    char* zchunk = (char*)alloc(zbytes);
    int*  counts  = (int*)zchunk;
    int*  startsP = (int*)(zchunk + N_ * sizeof(int));
    unsigned* meta2 = (unsigned*)alloc((size_t)NB_ * ROW * sizeof(unsigned)); // 3.93 MB
    unsigned* UVs1 = (unsigned*)alloc((size_t)H * N_ * sizeof(unsigned));
    unsigned* UVs2 = (unsigned*)alloc((size_t)H * N_ * sizeof(unsigned));
    unsigned* UVs3 = (unsigned*)alloc((size_t)H * N_ * sizeof(unsigned));
    float* Rs1 = (float*)alloc((size_t)H * N_ * sizeof(float));
    float* Rs2 = (float*)alloc((size_t)H * N_ * sizeof(float));
    float* Rs3 = (float*)alloc((size_t)H * N_ * sizeof(float));
    float* h1  = (float*)alloc((size_t)H * N_ * sizeof(float));   // slice-major
    float* h2  = (float*)alloc((size_t)H * N_ * sizeof(float));
    float* h3  = (float*)alloc((size_t)H * N_ * sizeof(float));

    hipMemsetAsync(zchunk, 0, zbytes, stream);

    k_build_pre1<<<EBLK + PBLK, 256, 0, stream>>>(ei, ea, x, batch,
                                                  nn_w1, nn_b1, root1, bias1,
                                                  counts, meta2, UVs1, Rs1, startsP);

    k_agg_lds<<<SLICES * CHUNKS, AT, 0, stream>>>(counts, meta2, UVs1, Rs1, h1);
    k_pre    <<<PBLK, 256, 0, stream>>>(h1, nn_w2, nn_b2, root2, bias2, UVs2, Rs2);
    k_agg_lds<<<SLICES * CHUNKS, AT, 0, stream>>>(counts, meta2, UVs2, Rs2, h2);
    k_pre    <<<PBLK, 256, 0, stream>>>(h2, nn_w3, nn_b3, root3, bias3, UVs3, Rs3);
    k_agg_lds<<<SLICES * CHUNKS, AT, 0, stream>>>(counts, meta2, UVs3, Rs3, h3);

    k_pool<<<G, 256, 0, stream>>>(h3, startsP, lin1_w, lin1_b, lin2_w, lin2_b, out);
}